// Round 8
// baseline (192.810 us; speedup 1.0000x reference)
//
#include <hip/hip_runtime.h>
#include <stdint.h>

typedef unsigned short u16;
typedef __attribute__((ext_vector_type(8))) short bf16x8;   // 8 bf16 = 4 VGPRs
typedef __attribute__((ext_vector_type(4))) float f32x4;

#define MFMA16(a, b, c) __builtin_amdgcn_mfma_f32_16x16x32_bf16((a), (b), (c), 0, 0, 0)
#define GLD16(gp, lp) __builtin_amdgcn_global_load_lds( \
    (__attribute__((address_space(1))) void*)(gp), \
    (__attribute__((address_space(3))) void*)(lp), 16, 0, 0)

__device__ __forceinline__ u16 f2b(float f) {   // fp32 -> bf16 RNE
  uint32_t u = __float_as_uint(f);
  u += 0x7FFFu + ((u >> 16) & 1u);
  return (u16)(u >> 16);
}
__device__ __forceinline__ uint32_t pk2(float lo, float hi) {  // 2xf32 -> packed bf16 (RNE)
  uint32_t r;
  asm("v_cvt_pk_bf16_f32 %0, %1, %2" : "=v"(r) : "v"(lo), "v"(hi));
  return r;
}
__device__ __forceinline__ float tanhfast(float x) {
  float e = __expf(2.f * x);
  return (e - 1.f) / (e + 1.f);
}

// ---------------- workspace layout (bytes) ----------------
// e1b bf16 [8192][640]              @ 0          10,485,760
// feat bf16 row-major [8192][3200]  @ 37748736   52,428,800   (k = co*100+pos)
// W1T FRAG [5 e][100 s][8 nb][64 l][8] @ 90177536  4,096,000  (k = d = s*32+q*8+j)
// W2T bf16 [5][128][128]            @ 94273536      163,840
// W2colF bf16 [5][2][64][8]         @ 94437376       10,240
// WcatT FRAG [100 s][64 l][8]       @ 94447616      102,400   (k = d)
// rw f32 [8192][5]                  @ 94550016      163,840   (total 94.7 MB)

// ============ prep: all weight repacks, one launch ============
__global__ __launch_bounds__(256) void prep_kernel(
    const float* __restrict__ c2w, const float* __restrict__ Wg,
    const float* __restrict__ Wglu, const float* __restrict__ W2e,
    const float* __restrict__ W1e, u16* __restrict__ W2colF,
    u16* __restrict__ WcatT, u16* __restrict__ W2T, u16* __restrict__ W1T) {
  int bid = blockIdx.x;
  if (bid < 540) {                      // ---- misc repacks ----
    int i = bid * 256 + threadIdx.x;
    if (i < 5120) {                     // conv2 B-fragments, k=(ky*3+kx)*16+ci, pad->160
      int j = i & 7, l = (i >> 3) & 63, nt = (i >> 9) & 1, s = i >> 10;
      int k = s * 32 + ((l >> 4) & 3) * 8 + j;
      int n = (l & 15) + nt * 16;
      float v = 0.f;
      if (k < 144) {
        int kykx = k >> 4, ci = k & 15;
        int ky = kykx / 3, kx = kykx - ky * 3;
        v = c2w[((n * 16 + ci) * 3 + ky) * 3 + kx];
      }
      W2colF[i] = f2b(v);
    } else if (i < 56320) {             // WcatT FRAG [s][l][8], k = d natural order
      int o = i - 5120;
      int s = o >> 9, rest = o & 511;
      int l = rest >> 3, j = rest & 7;
      int r = l & 15, c = (l >> 4) * 8 + j;
      int dref = s * 32 + c;            // natural feature index
      float v = 0.f;
      if (r < 5) v = Wg[dref * 5 + r];
      else if (r < 10) v = Wglu[dref * 5 + (r - 5)];
      WcatT[o] = f2b(v);
    } else if (i < 138240) {            // W2T[e][g][h]
      int o = i - 56320;
      int e = o >> 14, rem = o & 16383;
      int g = rem >> 7, h = rem & 127;
      W2T[o] = f2b(W2e[(e * 128 + h) * 128 + g]);
    }
  } else {                              // ---- W1e -> W1T FRAG [e][s][nb][l][8], k = d ----
    int tid = (bid - 540) * 256 + threadIdx.x;   // 256000 chunks of 16 B
    int l = tid & 63;
    int nb = (tid >> 6) & 7;
    int se = tid >> 9;                  // e*100 + s, < 500
    int s = se % 100, e = se / 100;
    int n = nb * 16 + (l & 15);
    int d0 = s * 32 + (l >> 4) * 8;
    const float* src = W1e + ((size_t)e * 3200 + d0) * 128 + n;
    u16 tmp[8];
#pragma unroll
    for (int j = 0; j < 8; j++) tmp[j] = f2b(src[j * 128]);
    *(uint4*)(W1T + (size_t)tid * 8) = *(const uint4*)tmp;
  }
}

// ============ conv v4b: 8-image pipeline, raw-LDS staging (frozen, round-7 verified) ============
#define CONV_IMG 8
__global__ __launch_bounds__(256, 4) void conv_fused_kernel(
    const float* __restrict__ x, const float* __restrict__ w1,
    const float* __restrict__ b1, const u16* __restrict__ W2colF,
    const float* __restrict__ b2, u16* __restrict__ feat) {
  __shared__ __align__(16) u16 cp[7232];   // [8 copies][28 rows][32], stride 904
  __shared__ __align__(16) u16 h1s[3456];  // pooled [144 pos][24]
  __shared__ __align__(16) float raw[784]; // raw f32 image (GLD16 dest), 3136 B
  int t = threadIdx.x, w = t >> 6, l = t & 63;
  int lm = l & 15;
  int b0 = blockIdx.x * CONV_IMG;

  int sr = (t * 171) >> 9;                 // t/3 (stager row)
  int so = t - sr * 3;                     // octet 0..2
  bool stager = t < 84;

  // async-stage image 0 (196 x 16B chunks, direct to LDS, no VGPRs held)
  if (t < 196) GLD16(x + (size_t)b0 * 784 + t * 4, &raw[w * 256]);

  // weights once per block (amortized over 8 images)
  bf16x8 bfr[5][2];
#pragma unroll
  for (int s = 0; s < 5; s++)
#pragma unroll
    for (int nt = 0; nt < 2; nt++)
      bfr[s][nt] = *(const bf16x8*)(W2colF + ((size_t)(s * 2 + nt) * 64 + l) * 8);

  int c = l & 7, ry = (l >> 3) & 1, q = l >> 4;
  bf16x8 bw1 = {0, 0, 0, 0, 0, 0, 0, 0}, bw2 = {0, 0, 0, 0, 0, 0, 0, 0};
#pragma unroll
  for (int j = 0; j < 5; j++) {
    bw1[j] = (short)f2b(w1[lm * 25 + q * 5 + j]);
    if (q == 0) bw2[j] = (short)f2b(w1[lm * 25 + 20 + j]);
  }
  float bias = b1[lm];

  int lq = l >> 4, hi = l >> 5;
  int cib = (lq & 1) * 8;
  int koff[5];
#pragma unroll
  for (int s = 0; s < 5; s++) {
    int kk = 2 * s + hi;
    if (kk > 8) kk = 8;                    // pad lanes: B-frag rows there are zero
    int ky = (kk * 11) >> 5;               // kk/3 for kk<=8
    int kx = kk - ky * 3;
    koff[s] = (ky * 12 + kx) * 24;
  }
  float bias0 = b2[lm], bias1 = b2[lm + 16];

#define SH(hi_, lo_) (((lo_) >> 16) | ((hi_) << 16))
#define PACKRAW                                                                 \
  if (stager) {                                                                 \
    const float4* src4 = (const float4*)&raw[sr * 28 + so * 8];                 \
    float4 qa = src4[0], qb = src4[1], qc = src4[2];                            \
    float4 qd = float4{0.f, 0.f, 0.f, 0.f};                                     \
    if (so < 2) qd = src4[3];                                                   \
    uint32_t d0 = pk2(qa.x, qa.y), d1 = pk2(qa.z, qa.w);                        \
    uint32_t d2 = pk2(qb.x, qb.y), d3 = pk2(qb.z, qb.w);                        \
    uint32_t d4 = pk2(qc.x, qc.y), d5 = pk2(qc.z, qc.w);                        \
    uint32_t d6 = pk2(qd.x, qd.y), d7 = pk2(qd.z, qd.w);                        \
    int base = sr * 32 + so * 8;                                                \
    *(uint4*)&cp[base + 0 * 904] = uint4{d0, d1, d2, d3};                       \
    *(uint4*)&cp[base + 1 * 904] = uint4{SH(d1, d0), SH(d2, d1), SH(d3, d2), SH(d4, d3)}; \
    *(uint4*)&cp[base + 2 * 904] = uint4{d1, d2, d3, d4};                       \
    *(uint4*)&cp[base + 3 * 904] = uint4{SH(d2, d1), SH(d3, d2), SH(d4, d3), SH(d5, d4)}; \
    *(uint4*)&cp[base + 4 * 904] = uint4{d2, d3, d4, d5};                       \
    *(uint4*)&cp[base + 5 * 904] = uint4{SH(d3, d2), SH(d4, d3), SH(d5, d4), SH(d6, d5)}; \
    *(uint4*)&cp[base + 6 * 904] = uint4{d3, d4, d5, d6};                       \
    *(uint4*)&cp[base + 7 * 904] = uint4{SH(d4, d3), SH(d5, d4), SH(d6, d5), SH(d7, d6)}; \
  }

  asm volatile("s_waitcnt vmcnt(0)" ::: "memory");
  __syncthreads();
  PACKRAW                                  // pack image 0
  __syncthreads();

  for (int ii = 0; ii < CONV_IMG; ii++) {
    // issue next image's raw load (lands under phase1; consumed by PACK in phase2)
    if (ii + 1 < CONV_IMG && t < 196)
      GLD16(x + (size_t)(b0 + ii + 1) * 784 + t * 4, &raw[w * 256]);

    // ---- phase 1: conv1 MFMA + pool -> h1s ----
#pragma unroll
    for (int i = 0; i < 9; i++) {
      int tt = i * 4 + w;                  // 36 tiles: p (pool-row) x xo (x-octet)
      int p = (tt * 171) >> 9;             // tt/3
      int xo = tt - p * 3;
      int r1 = p * 2 + ry + q;             // <= 26
      int r2 = min(r1 + 4, 27);            // clamp: rows >27 have zero weights
      bf16x8 a1 = *(const bf16x8*)&cp[c * 904 + r1 * 32 + xo * 8];
      bf16x8 a2 = *(const bf16x8*)&cp[c * 904 + r2 * 32 + xo * 8];
      f32x4 acc = {0.f, 0.f, 0.f, 0.f};
      acc = MFMA16(a1, bw1, acc);
      acc = MFMA16(a2, bw2, acc);
      float xm0 = fmaxf(acc[0], acc[1]);
      float xm1 = fmaxf(acc[2], acc[3]);
      float ym0 = fmaxf(xm0, __shfl_xor(xm0, 32));
      float ym1 = fmaxf(xm1, __shfl_xor(xm1, 32));
      if (l < 32) {
        int pos = p * 12 + xo * 4 + 2 * q;
        uint32_t pv = pk2(fmaxf(ym0 + bias, 0.f), fmaxf(ym1 + bias, 0.f));
        h1s[pos * 24 + lm]       = (u16)pv;
        h1s[(pos + 1) * 24 + lm] = (u16)(pv >> 16);
      }
    }
    // all waves' raw chunks must be resident before any stager reads them
    asm volatile("s_waitcnt vmcnt(0)" ::: "memory");
    __syncthreads();

    // ---- pack next image into cp (overlaps other waves' phase-2 MFMA) ----
    if (ii + 1 < CONV_IMG) PACKRAW

    // ---- phase 2: conv2 on h1s -> feat row-major ----
    u16* frow = feat + (size_t)(b0 + ii) * 3200;
#pragma unroll
    for (int tk = 0; tk < 2; tk++) {
      int ti = (3 - w) + tk * 4;           // wave0 (PACK-heavy) owns 1 tile only
      if (ti <= 6) {
        int p = ti * 16 + lm;
        int pc = p < 100 ? p : 99;         // clamp pad lanes (results discarded)
        int y = (pc * 205) >> 11;          // pc/10
        int xc = pc - y * 10;
        int abase = (y * 12 + xc) * 24 + cib;
        f32x4 acc0 = {0.f, 0.f, 0.f, 0.f}, acc1 = {0.f, 0.f, 0.f, 0.f};
#pragma unroll
        for (int s = 0; s < 5; s++) {
          bf16x8 a = *(const bf16x8*)&h1s[abase + koff[s]];
          acc0 = MFMA16(a, bfr[s][0], acc0);
          acc1 = MFMA16(a, bfr[s][1], acc1);
        }
        int pos0 = ti * 16 + lq * 4;
        if (pos0 < 100) {
          uint32_t w00 = pk2(fmaxf(acc0[0] + bias0, 0.f), fmaxf(acc0[1] + bias0, 0.f));
          uint32_t w01 = pk2(fmaxf(acc0[2] + bias0, 0.f), fmaxf(acc0[3] + bias0, 0.f));
          uint32_t w10 = pk2(fmaxf(acc1[0] + bias1, 0.f), fmaxf(acc1[1] + bias1, 0.f));
          uint32_t w11 = pk2(fmaxf(acc1[2] + bias1, 0.f), fmaxf(acc1[3] + bias1, 0.f));
          *(uint2*)(frow + lm * 100 + pos0)        = uint2{w00, w01};
          *(uint2*)(frow + (lm + 16) * 100 + pos0) = uint2{w10, w11};
        }
      }
    }
    __syncthreads();
  }
#undef PACKRAW
#undef SH
}

// ============ gemm1 v4: BK=64, 3-buffer GLD16 pipeline, depth-2 prefetch ============
// Stage step s+2 while waiting for step s's loads (vmcnt(14)=2 stages in flight):
// each step's loads get ~2 iterations (~500 cy) of cover instead of 1 — the r7
// counters showed 73% stall from depth-1 (MfmaUtil 27% = exactly the FLOP floor).
// LDS 3x26.6 = 80 KB -> 2 blocks/CU.
#define G1_STAGE(bufi, HASW)                                        \
  {                                                                 \
    GLD16(pA0, &lds[bufi][(w * 2 + 0) * 512]);                      \
    GLD16(pA1, &lds[bufi][(w * 2 + 1) * 512]);                      \
    GLD16(pB0, &lds[bufi][4096 + (w * 4 + 0) * 512]);               \
    GLD16(pB1, &lds[bufi][4096 + (w * 4 + 1) * 512]);               \
    GLD16(pB2, &lds[bufi][4096 + (w * 4 + 2) * 512]);               \
    GLD16(pB3, &lds[bufi][4096 + (w * 4 + 3) * 512]);               \
    if (HASW && w >= 2) GLD16(pW, &lds[bufi][12288 + (w - 2) * 512]);\
    pA0 += 64; pA1 += 64;                                           \
    pB0 += 8192; pB1 += 8192; pB2 += 8192; pB3 += 8192;             \
    pW += 1024;                                                     \
  }

#define G1_COMP(bufi, HASW)                                         \
  {                                                                 \
    const u16* st = &lds[bufi][0];                                  \
    bf16x8 af[2][2], bfv[2][4], wfv[2];                             \
    _Pragma("unroll")                                               \
    for (int i = 0; i < 2; i++) {                                   \
      int row = m_off + 16 * i + lm;                                \
      int rx = row & 7;                                             \
      af[i][0] = *(const bf16x8*)(st + row * 64 + ((lq ^ rx)) * 8); \
      af[i][1] = *(const bf16x8*)(st + row * 64 + (((4 + lq) ^ rx)) * 8); \
    }                                                               \
    _Pragma("unroll")                                               \
    for (int kk = 0; kk < 2; kk++)                                  \
      _Pragma("unroll")                                             \
      for (int j = 0; j < 4; j++)                                   \
        bfv[kk][j] = *(const bf16x8*)(st + 4096 + kk * 4096 +       \
                                      ((w >> 1) * 4 + j) * 512 + l * 8); \
    if (HASW && w < 2) {                                            \
      wfv[0] = *(const bf16x8*)(st + 12288 + l * 8);                \
      wfv[1] = *(const bf16x8*)(st + 12288 + 512 + l * 8);          \
    }                                                               \
    _Pragma("unroll")                                               \
    for (int kk = 0; kk < 2; kk++) {                                \
      _Pragma("unroll")                                             \
      for (int i = 0; i < 2; i++)                                   \
        _Pragma("unroll")                                           \
        for (int j = 0; j < 4; j++)                                 \
          acc[i][j] = MFMA16(af[i][kk], bfv[kk][j], acc[i][j]);     \
      if (HASW && w < 2) {                                          \
        racc[0] = MFMA16(af[0][kk], wfv[kk], racc[0]);              \
        racc[1] = MFMA16(af[1][kk], wfv[kk], racc[1]);              \
      }                                                             \
    }                                                               \
  }

// MODE 0: steady (stage s+2, wait 2 stages back); 1: penultimate; 2: last
#define G1_ITER(bufc, bufn, MODE, HASW)                             \
  {                                                                 \
    if ((MODE) == 0) {                                              \
      G1_STAGE(bufn, HASW)                                          \
      if (HASW && w >= 2)                                           \
        asm volatile("s_waitcnt vmcnt(14)" ::: "memory");           \
      else                                                          \
        asm volatile("s_waitcnt vmcnt(12)" ::: "memory");           \
    } else if ((MODE) == 1) {                                       \
      if (HASW && w >= 2)                                           \
        asm volatile("s_waitcnt vmcnt(7)" ::: "memory");            \
      else                                                          \
        asm volatile("s_waitcnt vmcnt(6)" ::: "memory");            \
    } else {                                                        \
      asm volatile("s_waitcnt vmcnt(0)" ::: "memory");              \
    }                                                               \
    asm volatile("s_barrier" ::: "memory");                         \
    G1_COMP(bufc, HASW)                                             \
    asm volatile("s_barrier" ::: "memory");                         \
  }

#define G1_PIPE(HASW)                                               \
  {                                                                 \
    G1_STAGE(0, HASW)                                               \
    G1_STAGE(1, HASW)                                               \
    for (int s3 = 0; s3 < 16; s3++) {                               \
      G1_ITER(0, 2, 0, HASW)                                        \
      G1_ITER(1, 0, 0, HASW)                                        \
      G1_ITER(2, 1, 0, HASW)                                        \
    }                                                               \
    G1_ITER(0, 2, 1, HASW)   /* step 48: no stage, wait step-48 */  \
    G1_ITER(1, 0, 2, HASW)   /* step 49: drain */                   \
  }

__global__ __launch_bounds__(256, 2) void gemm1_kernel(
    const u16* __restrict__ feat, const u16* __restrict__ W1T,
    const u16* __restrict__ WcatT, const float* __restrict__ b1e,
    const float* __restrict__ bg, const float* __restrict__ bglu,
    u16* __restrict__ e1b, float* __restrict__ rw) {
  // per buf: A [64 rows][8 chunk-of-16B swizzled] 8 KB | B 2x FRAG s-blocks 16 KB | W 2 KB
  __shared__ __align__(16) u16 lds[3][13312];     // 80 KB total (3 bufs)
  int t = threadIdx.x, w = t >> 6, l = t & 63;
  int mt = blockIdx.x & 127;
  int e = blockIdx.x >> 7;
  size_t m0 = (size_t)mt * 64;
  int lm = l & 15, lq = l >> 4;
  int m_off = (w & 1) * 32, n_off = (w >> 1) * 64;

  // A staging source: call c=w*2+i covers rows c*8..c*8+7; lane l -> row c*8+(l>>3),
  // dest chunk l&7, src chunk (l&7)^((l>>3)&7)  (XOR swizzle for bank-free reads)
  int rl = l >> 3, kd = l & 7, ksrc = kd ^ rl;
  const u16* pA0 = feat + (m0 + (size_t)(w * 2 + 0) * 8 + rl) * 3200 + ksrc * 8;
  const u16* pA1 = feat + (m0 + (size_t)(w * 2 + 1) * 8 + rl) * 3200 + ksrc * 8;
  const u16* pB0 = W1T + (size_t)e * 409600 + (w * 4 + 0) * 512 + l * 8;
  const u16* pB1 = W1T + (size_t)e * 409600 + (w * 4 + 1) * 512 + l * 8;
  const u16* pB2 = W1T + (size_t)e * 409600 + (w * 4 + 2) * 512 + l * 8;
  const u16* pB3 = W1T + (size_t)e * 409600 + (w * 4 + 3) * 512 + l * 8;
  const u16* pW  = WcatT + (w >= 2 ? (w - 2) * 512 : 0) + l * 8;

  f32x4 acc[2][4] = {};
  f32x4 racc[2] = {};

  if (e == 0) G1_PIPE(1)
  else        G1_PIPE(0)

  // epilogue: tanh+bias -> bf16, LDS transpose for vectorized stores
  float b1v[4];
#pragma unroll
  for (int j = 0; j < 4; j++) b1v[j] = b1e[e * 128 + n_off + 16 * j + lm];
  u16* E1t = &lds[0][0];                        // [64][128] u16 = 16 KB
  float* RACC = (float*)((char*)lds + 16384);   // [64][16] f32 = 4 KB (after E1t)
#pragma unroll
  for (int i = 0; i < 2; i++)
#pragma unroll
    for (int j = 0; j < 4; j++)
#pragma unroll
      for (int rr = 0; rr < 4; rr++) {
        int row = m_off + 16 * i + lq * 4 + rr;
        int col = n_off + 16 * j + lm;
        E1t[row * 128 + col] = f2b(tanhfast(acc[i][j][rr] + b1v[j]));
      }
  if (e == 0 && w < 2) {
#pragma unroll
    for (int i = 0; i < 2; i++)
#pragma unroll
      for (int rr = 0; rr < 4; rr++)
        RACC[(m_off + 16 * i + lq * 4 + rr) * 16 + lm] = racc[i][rr];
  }
  __syncthreads();
#pragma unroll
  for (int k2 = 0; k2 < 4; k2++) {
    int u = t + k2 * 256;                      // 1024 segs of 16B
    int row = u >> 4, sc = u & 15;
    uint4 v = *(const uint4*)(E1t + row * 128 + sc * 8);
    *(uint4*)(e1b + (m0 + row) * 640 + e * 128 + sc * 8) = v;
  }
  if (e == 0 && t < 64) {
    float gt[5];
#pragma unroll
    for (int ee = 0; ee < 5; ee++) {
      float va = RACC[t * 16 + ee] + bg[ee];
      float vb = RACC[t * 16 + 5 + ee] + bglu[ee];
      gt[ee] = va * (1.f / (1.f + __expf(-vb)));
    }
    float w3[3]; int i3[3];
    unsigned used = 0;
#pragma unroll
    for (int k = 0; k < 3; k++) {
      float best = -1e30f; int bi = 0;
#pragma unroll
      for (int ee = 0; ee < 5; ee++)
        if (!((used >> ee) & 1u) && gt[ee] > best) { best = gt[ee]; bi = ee; }
      used |= 1u << bi; w3[k] = best; i3[k] = bi;
    }
    float s1 = __expf(w3[1] - w3[0]), s2 = __expf(w3[2] - w3[0]);
    float inv = 1.f / (1.f + s1 + s2);
    float o[5] = {0.f, 0.f, 0.f, 0.f, 0.f};
    o[i3[0]] = inv; o[i3[1]] = s1 * inv; o[i3[2]] = s2 * inv;
#pragma unroll
    for (int ee = 0; ee < 5; ee++) rw[(m0 + t) * 5 + ee] = o[ee];
  }
}

// ============ gemm2 v2: W2 LDS-staged (GLD16, expert double-buffer, XOR swizzle) ============
// (unchanged — verified)
__global__ __launch_bounds__(256) void gemm2_head_kernel(
    const u16* __restrict__ e1b, const u16* __restrict__ W2T,
    const float* __restrict__ b2e, const float* __restrict__ rw,
    const float* __restrict__ Ws, const float* __restrict__ bs,
    float* __restrict__ out) {
  __shared__ u16 E1s[32][648];                    // 41.5 KB, overlaid by moes/parts later
  __shared__ __align__(16) u16 w2s[2][16384];     // 64 KB: per-expert slab double buffer
  __shared__ float wssh[1280];
  __shared__ float rws[160];
  int t = threadIdx.x, w = t >> 6, l = t & 63;
  int r0 = blockIdx.x * 32;
  int lm = l & 15, lq = l >> 4, mh = (w & 1), nh = (w >> 1);

  // stage expert 0 W2 first (GLD16, inverse-swizzled source, linear dest)
  // swizzle: byte' = byte ^ (((byte>>8)&7)<<4)  (involution within each 256 B row)
#pragma unroll
  for (int c2 = 0; c2 < 8; c2++) {
    int o = w * 8192 + c2 * 1024 + l * 16;
    int src = o ^ (((o >> 8) & 7) << 4);
    GLD16(W2T + (src >> 1), (u16*)w2s[0] + (o >> 1));
  }
  // preload all bias values (hides b2e latency outside the expert loop)
  float b2v[5][4];
#pragma unroll
  for (int e = 0; e < 5; e++)
#pragma unroll
    for (int j = 0; j < 4; j++) b2v[e][j] = b2e[e * 128 + nh * 64 + 16 * j + lm];
  {
    int row = t >> 3;
    const u16* src = e1b + (size_t)(r0 + row) * 640 + (t & 7) * 8;
    u16* drow = &E1s[row][(t & 7) * 8];
#pragma unroll
    for (int k = 0; k < 10; k++)
      *(uint4*)(drow + k * 64) = *(const uint4*)(src + k * 64);
  }
  if (t < 160) rws[t] = rw[r0 * 5 + t];
  for (int i = t; i < 1280; i += 256) wssh[i] = Ws[i];
  __syncthreads();                     // drains all (vmcnt 0 here)

  f32x4 moeacc[4] = {};
#pragma unroll
  for (int e = 0; e < 5; e++) {
    if (e < 4) {                       // prefetch next expert slab
      const u16* w2g = W2T + (e + 1) * 16384;
#pragma unroll
      for (int c2 = 0; c2 < 8; c2++) {
        int o = w * 8192 + c2 * 1024 + l * 16;
        int src = o ^ (((o >> 8) & 7) << 4);
        GLD16(w2g + (src >> 1), (u16*)w2s[(e + 1) & 1] + (o >> 1));
      }
      asm volatile("s_waitcnt vmcnt(8)" ::: "memory");   // current slab resident
    } else {
      asm volatile("s_waitcnt vmcnt(0)" ::: "memory");
    }
    asm volatile("s_barrier" ::: "memory");
    const char* wb = (const char*)w2s[e & 1];
    f32x4 acc[4] = {};
#pragma unroll
    for (int kk = 0; kk < 4; kk++) {
      bf16x8 a = *(const bf16x8*)&E1s[mh * 16 + lm][e * 128 + kk * 32 + lq * 8];
#pragma unroll
      for (int j = 0; j < 4; j++) {
        int n = nh * 64 + 16 * j + lm;
        int ba = (n * 256 + kk * 64 + lq * 16) ^ ((n & 7) << 4);
        bf16x8 b = *(const bf16x8*)(wb + ba);
        acc[j] = MFMA16(a, b, acc[j]);
      }
    }
#pragma unroll
    for (int j = 0; j < 4; j++)
#pragma unroll
      for (int rr = 0; rr < 4; rr++) {
        float v = tanhfast(acc[j][rr] + b2v[e][j]);
        moeacc[j][rr] += rws[(mh * 16 + lq * 4 + rr) * 5 + e] * v;
      }
    asm volatile("s_barrier" ::: "memory");  // slab consumed; safe to overwrite next iter
  }
  __syncthreads();                     // done reading E1s
  float* moes = (float*)&E1s[0][0];    // [32][132]
#pragma unroll
  for (int j = 0; j < 4; j++)
#pragma unroll
    for (int rr = 0; rr < 4; rr++)
      moes[(mh * 16 + lq * 4 + rr) * 132 + nh * 64 + 16 * j + lm] = moeacc[j][rr];
  __syncthreads();
  float* parts = moes + 32 * 132;      // [32][4][10]
  if (t < 128) {
    int row = t >> 2, qc = t & 3;
    float pl[10] = {};
    for (int cc = qc * 32; cc < qc * 32 + 32; cc++) {
      float mv = moes[row * 132 + cc];
#pragma unroll
      for (int cls = 0; cls < 10; cls++) pl[cls] += mv * wssh[cc * 10 + cls];
    }
#pragma unroll
    for (int cls = 0; cls < 10; cls++) parts[(row * 4 + qc) * 10 + cls] = pl[cls];
  }
  __syncthreads();
  if (t < 32) {
    float lg[10];
    float mx = -1e30f;
#pragma unroll
    for (int cls = 0; cls < 10; cls++) {
      lg[cls] = parts[(t * 4) * 10 + cls] + parts[(t * 4 + 1) * 10 + cls] +
                parts[(t * 4 + 2) * 10 + cls] + parts[(t * 4 + 3) * 10 + cls] + bs[cls];
      mx = fmaxf(mx, lg[cls]);
    }
    float sum = 0.f;
#pragma unroll
    for (int cls = 0; cls < 10; cls++) { lg[cls] = __expf(lg[cls] - mx); sum += lg[cls]; }
    float inv = 1.f / sum;
    float* orow = out + (size_t)(r0 + t) * 10;
#pragma unroll
    for (int cls = 0; cls < 10; cls++) orow[cls] = lg[cls] * inv;
  }
}

extern "C" void kernel_launch(void* const* d_in, const int* in_sizes, int n_in,
                              void* d_out, int out_size, void* d_ws, size_t ws_size,
                              hipStream_t stream) {
  const float* x    = (const float*)d_in[0];
  const float* c1w  = (const float*)d_in[1];
  const float* c1b  = (const float*)d_in[2];
  const float* c2w  = (const float*)d_in[3];
  const float* c2b  = (const float*)d_in[4];
  const float* Wg   = (const float*)d_in[5];
  const float* bg   = (const float*)d_in[6];
  const float* Wglu = (const float*)d_in[7];
  const float* bglu = (const float*)d_in[8];
  const float* W1e  = (const float*)d_in[9];
  const float* b1e  = (const float*)d_in[10];
  const float* W2e  = (const float*)d_in[11];
  const float* b2e  = (const float*)d_in[12];
  const float* Wsp  = (const float*)d_in[13];
  const float* bsp  = (const float*)d_in[14];
  char* ws = (char*)d_ws;
  u16* e1b     = (u16*)(ws + 0);
  u16* feat    = (u16*)(ws + 37748736);
  u16* W1T     = (u16*)(ws + 90177536);
  u16* W2T     = (u16*)(ws + 94273536);
  u16* W2colF  = (u16*)(ws + 94437376);
  u16* WcatT   = (u16*)(ws + 94447616);
  float* rw    = (float*)(ws + 94550016);

  prep_kernel<<<1540, 256, 0, stream>>>(c2w, Wg, Wglu, W2e, W1e,
                                        W2colF, WcatT, W2T, W1T);
  conv_fused_kernel<<<1024, 256, 0, stream>>>(x, c1w, c1b, W2colF, c2b, feat);
  gemm1_kernel<<<640, 256, 0, stream>>>(feat, W1T, WcatT, b1e, bg, bglu, e1b, rw);
  gemm2_head_kernel<<<256, 256, 0, stream>>>(e1b, W2T, b2e, rw, Wsp, bsp,
                                             (float*)d_out);
}

// Round 9
// 189.519 us; speedup vs baseline: 1.0174x; 1.0174x over previous
//
#include <hip/hip_runtime.h>
#include <stdint.h>

typedef unsigned short u16;
typedef __attribute__((ext_vector_type(8))) short bf16x8;   // 8 bf16 = 4 VGPRs
typedef __attribute__((ext_vector_type(4))) float f32x4;

#define MFMA16(a, b, c) __builtin_amdgcn_mfma_f32_16x16x32_bf16((a), (b), (c), 0, 0, 0)
#define GLD16(gp, lp) __builtin_amdgcn_global_load_lds( \
    (__attribute__((address_space(1))) void*)(gp), \
    (__attribute__((address_space(3))) void*)(lp), 16, 0, 0)

__device__ __forceinline__ u16 f2b(float f) {   // fp32 -> bf16 RNE
  uint32_t u = __float_as_uint(f);
  u += 0x7FFFu + ((u >> 16) & 1u);
  return (u16)(u >> 16);
}
__device__ __forceinline__ uint32_t pk2(float lo, float hi) {  // 2xf32 -> packed bf16 (RNE)
  uint32_t r;
  asm("v_cvt_pk_bf16_f32 %0, %1, %2" : "=v"(r) : "v"(lo), "v"(hi));
  return r;
}
__device__ __forceinline__ float tanhfast(float x) {
  float e = __expf(2.f * x);
  return (e - 1.f) / (e + 1.f);
}

// ---------------- workspace layout (bytes) ----------------
// e1b bf16 [8192][640]              @ 0          10,485,760
// feat bf16 row-major [8192][3200]  @ 37748736   52,428,800   (k = co*100+pos)
// W1T FRAG [5 e][100 s][8 nb][64 l][8] @ 90177536  4,096,000  (k = d = s*32+q*8+j)
// W2T bf16 [5][128][128]            @ 94273536      163,840
// W2colF bf16 [5][2][64][8]         @ 94437376       10,240
// WcatT FRAG [100 s][64 l][8]       @ 94447616      102,400   (k = d)
// rw f32 [8192][5]                  @ 94550016      163,840   (total 94.7 MB)

// ============ prep: all weight repacks, one launch ============
__global__ __launch_bounds__(256) void prep_kernel(
    const float* __restrict__ c2w, const float* __restrict__ Wg,
    const float* __restrict__ Wglu, const float* __restrict__ W2e,
    const float* __restrict__ W1e, u16* __restrict__ W2colF,
    u16* __restrict__ WcatT, u16* __restrict__ W2T, u16* __restrict__ W1T) {
  int bid = blockIdx.x;
  if (bid < 540) {                      // ---- misc repacks ----
    int i = bid * 256 + threadIdx.x;
    if (i < 5120) {                     // conv2 B-fragments, k=(ky*3+kx)*16+ci, pad->160
      int j = i & 7, l = (i >> 3) & 63, nt = (i >> 9) & 1, s = i >> 10;
      int k = s * 32 + ((l >> 4) & 3) * 8 + j;
      int n = (l & 15) + nt * 16;
      float v = 0.f;
      if (k < 144) {
        int kykx = k >> 4, ci = k & 15;
        int ky = kykx / 3, kx = kykx - ky * 3;
        v = c2w[((n * 16 + ci) * 3 + ky) * 3 + kx];
      }
      W2colF[i] = f2b(v);
    } else if (i < 56320) {             // WcatT FRAG [s][l][8], k = d natural order
      int o = i - 5120;
      int s = o >> 9, rest = o & 511;
      int l = rest >> 3, j = rest & 7;
      int r = l & 15, c = (l >> 4) * 8 + j;
      int dref = s * 32 + c;            // natural feature index
      float v = 0.f;
      if (r < 5) v = Wg[dref * 5 + r];
      else if (r < 10) v = Wglu[dref * 5 + (r - 5)];
      WcatT[o] = f2b(v);
    } else if (i < 138240) {            // W2T[e][g][h]
      int o = i - 56320;
      int e = o >> 14, rem = o & 16383;
      int g = rem >> 7, h = rem & 127;
      W2T[o] = f2b(W2e[(e * 128 + h) * 128 + g]);
    }
  } else {                              // ---- W1e -> W1T FRAG [e][s][nb][l][8], k = d ----
    int tid = (bid - 540) * 256 + threadIdx.x;   // 256000 chunks of 16 B
    int l = tid & 63;
    int nb = (tid >> 6) & 7;
    int se = tid >> 9;                  // e*100 + s, < 500
    int s = se % 100, e = se / 100;
    int n = nb * 16 + (l & 15);
    int d0 = s * 32 + (l >> 4) * 8;
    const float* src = W1e + ((size_t)e * 3200 + d0) * 128 + n;
    u16 tmp[8];
#pragma unroll
    for (int j = 0; j < 8; j++) tmp[j] = f2b(src[j * 128]);
    *(uint4*)(W1T + (size_t)tid * 8) = *(const uint4*)tmp;
  }
}

// ============ conv v4b: 8-image pipeline, raw-LDS staging (frozen, round-7 verified) ============
#define CONV_IMG 8
__global__ __launch_bounds__(256, 4) void conv_fused_kernel(
    const float* __restrict__ x, const float* __restrict__ w1,
    const float* __restrict__ b1, const u16* __restrict__ W2colF,
    const float* __restrict__ b2, u16* __restrict__ feat) {
  __shared__ __align__(16) u16 cp[7232];   // [8 copies][28 rows][32], stride 904
  __shared__ __align__(16) u16 h1s[3456];  // pooled [144 pos][24]
  __shared__ __align__(16) float raw[784]; // raw f32 image (GLD16 dest), 3136 B
  int t = threadIdx.x, w = t >> 6, l = t & 63;
  int lm = l & 15;
  int b0 = blockIdx.x * CONV_IMG;

  int sr = (t * 171) >> 9;                 // t/3 (stager row)
  int so = t - sr * 3;                     // octet 0..2
  bool stager = t < 84;

  // async-stage image 0 (196 x 16B chunks, direct to LDS, no VGPRs held)
  if (t < 196) GLD16(x + (size_t)b0 * 784 + t * 4, &raw[w * 256]);

  // weights once per block (amortized over 8 images)
  bf16x8 bfr[5][2];
#pragma unroll
  for (int s = 0; s < 5; s++)
#pragma unroll
    for (int nt = 0; nt < 2; nt++)
      bfr[s][nt] = *(const bf16x8*)(W2colF + ((size_t)(s * 2 + nt) * 64 + l) * 8);

  int c = l & 7, ry = (l >> 3) & 1, q = l >> 4;
  bf16x8 bw1 = {0, 0, 0, 0, 0, 0, 0, 0}, bw2 = {0, 0, 0, 0, 0, 0, 0, 0};
#pragma unroll
  for (int j = 0; j < 5; j++) {
    bw1[j] = (short)f2b(w1[lm * 25 + q * 5 + j]);
    if (q == 0) bw2[j] = (short)f2b(w1[lm * 25 + 20 + j]);
  }
  float bias = b1[lm];

  int lq = l >> 4, hi = l >> 5;
  int cib = (lq & 1) * 8;
  int koff[5];
#pragma unroll
  for (int s = 0; s < 5; s++) {
    int kk = 2 * s + hi;
    if (kk > 8) kk = 8;                    // pad lanes: B-frag rows there are zero
    int ky = (kk * 11) >> 5;               // kk/3 for kk<=8
    int kx = kk - ky * 3;
    koff[s] = (ky * 12 + kx) * 24;
  }
  float bias0 = b2[lm], bias1 = b2[lm + 16];

#define SH(hi_, lo_) (((lo_) >> 16) | ((hi_) << 16))
#define PACKRAW                                                                 \
  if (stager) {                                                                 \
    const float4* src4 = (const float4*)&raw[sr * 28 + so * 8];                 \
    float4 qa = src4[0], qb = src4[1], qc = src4[2];                            \
    float4 qd = float4{0.f, 0.f, 0.f, 0.f};                                     \
    if (so < 2) qd = src4[3];                                                   \
    uint32_t d0 = pk2(qa.x, qa.y), d1 = pk2(qa.z, qa.w);                        \
    uint32_t d2 = pk2(qb.x, qb.y), d3 = pk2(qb.z, qb.w);                        \
    uint32_t d4 = pk2(qc.x, qc.y), d5 = pk2(qc.z, qc.w);                        \
    uint32_t d6 = pk2(qd.x, qd.y), d7 = pk2(qd.z, qd.w);                        \
    int base = sr * 32 + so * 8;                                                \
    *(uint4*)&cp[base + 0 * 904] = uint4{d0, d1, d2, d3};                       \
    *(uint4*)&cp[base + 1 * 904] = uint4{SH(d1, d0), SH(d2, d1), SH(d3, d2), SH(d4, d3)}; \
    *(uint4*)&cp[base + 2 * 904] = uint4{d1, d2, d3, d4};                       \
    *(uint4*)&cp[base + 3 * 904] = uint4{SH(d2, d1), SH(d3, d2), SH(d4, d3), SH(d5, d4)}; \
    *(uint4*)&cp[base + 4 * 904] = uint4{d2, d3, d4, d5};                       \
    *(uint4*)&cp[base + 5 * 904] = uint4{SH(d3, d2), SH(d4, d3), SH(d5, d4), SH(d6, d5)}; \
    *(uint4*)&cp[base + 6 * 904] = uint4{d3, d4, d5, d6};                       \
    *(uint4*)&cp[base + 7 * 904] = uint4{SH(d4, d3), SH(d5, d4), SH(d6, d5), SH(d7, d6)}; \
  }

  asm volatile("s_waitcnt vmcnt(0)" ::: "memory");
  __syncthreads();
  PACKRAW                                  // pack image 0
  __syncthreads();

  for (int ii = 0; ii < CONV_IMG; ii++) {
    // issue next image's raw load (lands under phase1; consumed by PACK in phase2)
    if (ii + 1 < CONV_IMG && t < 196)
      GLD16(x + (size_t)(b0 + ii + 1) * 784 + t * 4, &raw[w * 256]);

    // ---- phase 1: conv1 MFMA + pool -> h1s ----
#pragma unroll
    for (int i = 0; i < 9; i++) {
      int tt = i * 4 + w;                  // 36 tiles: p (pool-row) x xo (x-octet)
      int p = (tt * 171) >> 9;             // tt/3
      int xo = tt - p * 3;
      int r1 = p * 2 + ry + q;             // <= 26
      int r2 = min(r1 + 4, 27);            // clamp: rows >27 have zero weights
      bf16x8 a1 = *(const bf16x8*)&cp[c * 904 + r1 * 32 + xo * 8];
      bf16x8 a2 = *(const bf16x8*)&cp[c * 904 + r2 * 32 + xo * 8];
      f32x4 acc = {0.f, 0.f, 0.f, 0.f};
      acc = MFMA16(a1, bw1, acc);
      acc = MFMA16(a2, bw2, acc);
      float xm0 = fmaxf(acc[0], acc[1]);
      float xm1 = fmaxf(acc[2], acc[3]);
      float ym0 = fmaxf(xm0, __shfl_xor(xm0, 32));
      float ym1 = fmaxf(xm1, __shfl_xor(xm1, 32));
      if (l < 32) {
        int pos = p * 12 + xo * 4 + 2 * q;
        uint32_t pv = pk2(fmaxf(ym0 + bias, 0.f), fmaxf(ym1 + bias, 0.f));
        h1s[pos * 24 + lm]       = (u16)pv;
        h1s[(pos + 1) * 24 + lm] = (u16)(pv >> 16);
      }
    }
    // all waves' raw chunks must be resident before any stager reads them
    asm volatile("s_waitcnt vmcnt(0)" ::: "memory");
    __syncthreads();

    // ---- pack next image into cp (overlaps other waves' phase-2 MFMA) ----
    if (ii + 1 < CONV_IMG) PACKRAW

    // ---- phase 2: conv2 on h1s -> feat row-major ----
    u16* frow = feat + (size_t)(b0 + ii) * 3200;
#pragma unroll
    for (int tk = 0; tk < 2; tk++) {
      int ti = (3 - w) + tk * 4;           // wave0 (PACK-heavy) owns 1 tile only
      if (ti <= 6) {
        int p = ti * 16 + lm;
        int pc = p < 100 ? p : 99;         // clamp pad lanes (results discarded)
        int y = (pc * 205) >> 11;          // pc/10
        int xc = pc - y * 10;
        int abase = (y * 12 + xc) * 24 + cib;
        f32x4 acc0 = {0.f, 0.f, 0.f, 0.f}, acc1 = {0.f, 0.f, 0.f, 0.f};
#pragma unroll
        for (int s = 0; s < 5; s++) {
          bf16x8 a = *(const bf16x8*)&h1s[abase + koff[s]];
          acc0 = MFMA16(a, bfr[s][0], acc0);
          acc1 = MFMA16(a, bfr[s][1], acc1);
        }
        int pos0 = ti * 16 + lq * 4;
        if (pos0 < 100) {
          uint32_t w00 = pk2(fmaxf(acc0[0] + bias0, 0.f), fmaxf(acc0[1] + bias0, 0.f));
          uint32_t w01 = pk2(fmaxf(acc0[2] + bias0, 0.f), fmaxf(acc0[3] + bias0, 0.f));
          uint32_t w10 = pk2(fmaxf(acc1[0] + bias1, 0.f), fmaxf(acc1[1] + bias1, 0.f));
          uint32_t w11 = pk2(fmaxf(acc1[2] + bias1, 0.f), fmaxf(acc1[3] + bias1, 0.f));
          *(uint2*)(frow + lm * 100 + pos0)        = uint2{w00, w01};
          *(uint2*)(frow + (lm + 16) * 100 + pos0) = uint2{w10, w11};
        }
      }
    }
    __syncthreads();
  }
#undef PACKRAW
#undef SH
}

// ============ gemm1 v5: 128x128 tile, BK=64, GLD16 double-buffer ============
// Retile from 64x128: staged traffic 524->393 MB (B-dup halves), 2x MFMA per
// step amortizes the per-step barrier/latency overhead (r8 showed depth!=fix).
// 4 waves map to 64x64 quadrants (wr=w&1, wc=w>>1); acc[4][4] per wave.
// Same-mt blocks are 64 apart (64%8==0 -> same XCD, A shared in L2).
// LDS per buf: A[128][64] 16 KB | B 2 s-blocks 16 KB | W 2x512 2 KB -> 2 bufs 68 KB.
#define G1_STAGE(bufi, HASW)                                        \
  {                                                                 \
    GLD16(pA0, &lds[bufi][(w * 4 + 0) * 512]);                      \
    GLD16(pA1, &lds[bufi][(w * 4 + 1) * 512]);                      \
    GLD16(pA2, &lds[bufi][(w * 4 + 2) * 512]);                      \
    GLD16(pA3, &lds[bufi][(w * 4 + 3) * 512]);                      \
    GLD16(pB0, &lds[bufi][8192 + (w * 4 + 0) * 512]);               \
    GLD16(pB1, &lds[bufi][8192 + (w * 4 + 1) * 512]);               \
    GLD16(pB2, &lds[bufi][8192 + (w * 4 + 2) * 512]);               \
    GLD16(pB3, &lds[bufi][8192 + (w * 4 + 3) * 512]);               \
    if (HASW && w >= 2) GLD16(pW, &lds[bufi][16384 + (w - 2) * 512]);\
    pA0 += 64; pA1 += 64; pA2 += 64; pA3 += 64;                     \
    pB0 += 8192; pB1 += 8192; pB2 += 8192; pB3 += 8192;             \
    pW += 1024;                                                     \
  }

#define G1_COMP(bufi, HASW)                                         \
  {                                                                 \
    const u16* st = &lds[bufi][0];                                  \
    _Pragma("unroll")                                               \
    for (int kk = 0; kk < 2; kk++) {                                \
      bf16x8 af[4], bfv[4], wfv;                                    \
      _Pragma("unroll")                                             \
      for (int i = 0; i < 4; i++) {                                 \
        int row = m_off + 16 * i + lm;                              \
        af[i] = *(const bf16x8*)(st + row * 64 +                    \
                                 ((kk * 4 + lq) ^ (lm & 7)) * 8);   \
      }                                                             \
      _Pragma("unroll")                                             \
      for (int j = 0; j < 4; j++)                                   \
        bfv[j] = *(const bf16x8*)(st + 8192 + kk * 4096 +           \
                                  (wc4 + j) * 512 + l * 8);         \
      if (HASW && w < 2)                                            \
        wfv = *(const bf16x8*)(st + 16384 + kk * 512 + l * 8);      \
      _Pragma("unroll")                                             \
      for (int i = 0; i < 4; i++)                                   \
        _Pragma("unroll")                                           \
        for (int j = 0; j < 4; j++)                                 \
          acc[i][j] = MFMA16(af[i], bfv[j], acc[i][j]);             \
      if (HASW && w < 2) {                                          \
        _Pragma("unroll")                                           \
        for (int i = 0; i < 4; i++)                                 \
          racc[i] = MFMA16(af[i], wfv, racc[i]);                    \
      }                                                             \
    }                                                               \
  }

#define G1_PIPE(HASW)                                               \
  {                                                                 \
    G1_STAGE(0, HASW)                                               \
    for (int s = 0; s < 50; s++) {                                  \
      int buf = s & 1;                                              \
      if (s < 49) {                                                 \
        G1_STAGE(buf ^ 1, HASW)                                     \
        if (HASW && w >= 2)                                         \
          asm volatile("s_waitcnt vmcnt(9)" ::: "memory");          \
        else                                                        \
          asm volatile("s_waitcnt vmcnt(8)" ::: "memory");          \
      } else {                                                      \
        asm volatile("s_waitcnt vmcnt(0)" ::: "memory");            \
      }                                                             \
      asm volatile("s_barrier" ::: "memory");                       \
      G1_COMP(buf, HASW)                                            \
      asm volatile("s_barrier" ::: "memory");                      \
    }                                                               \
  }

__global__ __launch_bounds__(256, 2) void gemm1_kernel(
    const u16* __restrict__ feat, const u16* __restrict__ W1T,
    const u16* __restrict__ WcatT, const float* __restrict__ b1e,
    const float* __restrict__ bg, const float* __restrict__ bglu,
    u16* __restrict__ e1b, float* __restrict__ rw) {
  __shared__ __align__(16) u16 lds[2][17408];     // 68 KB total
  int t = threadIdx.x, w = t >> 6, l = t & 63;
  int mt = blockIdx.x & 63;
  int e = blockIdx.x >> 6;
  size_t m0 = (size_t)mt * 128;
  int lm = l & 15, lq = l >> 4;
  int wr = w & 1, wc = w >> 1;
  int m_off = wr * 64, n_off = wc * 64, wc4 = wc * 4;

  // A staging: call c=w*4+i covers rows c*8..c*8+7; lane l -> row c*8+(l>>3),
  // dest chunk l&7, src chunk (l&7)^((l>>3)&7)  (XOR swizzle for bank-free reads)
  int rl = l >> 3, kd = l & 7, ksrc = kd ^ rl;
  const u16* pA0 = feat + (m0 + (size_t)(w * 4 + 0) * 8 + rl) * 3200 + ksrc * 8;
  const u16* pA1 = feat + (m0 + (size_t)(w * 4 + 1) * 8 + rl) * 3200 + ksrc * 8;
  const u16* pA2 = feat + (m0 + (size_t)(w * 4 + 2) * 8 + rl) * 3200 + ksrc * 8;
  const u16* pA3 = feat + (m0 + (size_t)(w * 4 + 3) * 8 + rl) * 3200 + ksrc * 8;
  const u16* pB0 = W1T + (size_t)e * 409600 + (w * 4 + 0) * 512 + l * 8;
  const u16* pB1 = W1T + (size_t)e * 409600 + (w * 4 + 1) * 512 + l * 8;
  const u16* pB2 = W1T + (size_t)e * 409600 + (w * 4 + 2) * 512 + l * 8;
  const u16* pB3 = W1T + (size_t)e * 409600 + (w * 4 + 3) * 512 + l * 8;
  const u16* pW  = WcatT + (w >= 2 ? (w - 2) * 512 : 0) + l * 8;

  f32x4 acc[4][4] = {};
  f32x4 racc[4] = {};

  if (e == 0) G1_PIPE(1)
  else        G1_PIPE(0)

  // epilogue: tanh+bias -> bf16, LDS transpose for vectorized stores
  float b1v[4];
#pragma unroll
  for (int j = 0; j < 4; j++) b1v[j] = b1e[e * 128 + n_off + 16 * j + lm];
  u16* E1t = &lds[0][0];                        // [128][128] u16 = 32 KB
  float* RACC = (float*)((char*)lds + 34816);   // [128][16] f32 = 8 KB
#pragma unroll
  for (int i = 0; i < 4; i++)
#pragma unroll
    for (int j = 0; j < 4; j++)
#pragma unroll
      for (int rr = 0; rr < 4; rr++) {
        int row = m_off + 16 * i + lq * 4 + rr;
        int col = n_off + 16 * j + lm;
        E1t[row * 128 + col] = f2b(tanhfast(acc[i][j][rr] + b1v[j]));
      }
  if (e == 0 && w < 2) {
#pragma unroll
    for (int i = 0; i < 4; i++)
#pragma unroll
      for (int rr = 0; rr < 4; rr++)
        RACC[(m_off + 16 * i + lq * 4 + rr) * 16 + lm] = racc[i][rr];
  }
  __syncthreads();
#pragma unroll
  for (int k2 = 0; k2 < 8; k2++) {
    int u = t + k2 * 256;                      // 2048 segs of 16B
    int row = u >> 4, sc = u & 15;
    uint4 v = *(const uint4*)(E1t + row * 128 + sc * 8);
    *(uint4*)(e1b + (m0 + row) * 640 + e * 128 + sc * 8) = v;
  }
  if (e == 0 && t < 128) {
    float gt[5];
#pragma unroll
    for (int ee = 0; ee < 5; ee++) {
      float va = RACC[t * 16 + ee] + bg[ee];
      float vb = RACC[t * 16 + 5 + ee] + bglu[ee];
      gt[ee] = va * (1.f / (1.f + __expf(-vb)));
    }
    float w3[3]; int i3[3];
    unsigned used = 0;
#pragma unroll
    for (int k = 0; k < 3; k++) {
      float best = -1e30f; int bi = 0;
#pragma unroll
      for (int ee = 0; ee < 5; ee++)
        if (!((used >> ee) & 1u) && gt[ee] > best) { best = gt[ee]; bi = ee; }
      used |= 1u << bi; w3[k] = best; i3[k] = bi;
    }
    float s1 = __expf(w3[1] - w3[0]), s2 = __expf(w3[2] - w3[0]);
    float inv = 1.f / (1.f + s1 + s2);
    float o[5] = {0.f, 0.f, 0.f, 0.f, 0.f};
    o[i3[0]] = inv; o[i3[1]] = s1 * inv; o[i3[2]] = s2 * inv;
#pragma unroll
    for (int ee = 0; ee < 5; ee++) rw[(m0 + t) * 5 + ee] = o[ee];
  }
}

// ============ gemm2 v2: W2 LDS-staged (GLD16, expert double-buffer, XOR swizzle) ============
// (unchanged — verified)
__global__ __launch_bounds__(256) void gemm2_head_kernel(
    const u16* __restrict__ e1b, const u16* __restrict__ W2T,
    const float* __restrict__ b2e, const float* __restrict__ rw,
    const float* __restrict__ Ws, const float* __restrict__ bs,
    float* __restrict__ out) {
  __shared__ u16 E1s[32][648];                    // 41.5 KB, overlaid by moes/parts later
  __shared__ __align__(16) u16 w2s[2][16384];     // 64 KB: per-expert slab double buffer
  __shared__ float wssh[1280];
  __shared__ float rws[160];
  int t = threadIdx.x, w = t >> 6, l = t & 63;
  int r0 = blockIdx.x * 32;
  int lm = l & 15, lq = l >> 4, mh = (w & 1), nh = (w >> 1);

  // stage expert 0 W2 first (GLD16, inverse-swizzled source, linear dest)
  // swizzle: byte' = byte ^ (((byte>>8)&7)<<4)  (involution within each 256 B row)
#pragma unroll
  for (int c2 = 0; c2 < 8; c2++) {
    int o = w * 8192 + c2 * 1024 + l * 16;
    int src = o ^ (((o >> 8) & 7) << 4);
    GLD16(W2T + (src >> 1), (u16*)w2s[0] + (o >> 1));
  }
  // preload all bias values (hides b2e latency outside the expert loop)
  float b2v[5][4];
#pragma unroll
  for (int e = 0; e < 5; e++)
#pragma unroll
    for (int j = 0; j < 4; j++) b2v[e][j] = b2e[e * 128 + nh * 64 + 16 * j + lm];
  {
    int row = t >> 3;
    const u16* src = e1b + (size_t)(r0 + row) * 640 + (t & 7) * 8;
    u16* drow = &E1s[row][(t & 7) * 8];
#pragma unroll
    for (int k = 0; k < 10; k++)
      *(uint4*)(drow + k * 64) = *(const uint4*)(src + k * 64);
  }
  if (t < 160) rws[t] = rw[r0 * 5 + t];
  for (int i = t; i < 1280; i += 256) wssh[i] = Ws[i];
  __syncthreads();                     // drains all (vmcnt 0 here)

  f32x4 moeacc[4] = {};
#pragma unroll
  for (int e = 0; e < 5; e++) {
    if (e < 4) {                       // prefetch next expert slab
      const u16* w2g = W2T + (e + 1) * 16384;
#pragma unroll
      for (int c2 = 0; c2 < 8; c2++) {
        int o = w * 8192 + c2 * 1024 + l * 16;
        int src = o ^ (((o >> 8) & 7) << 4);
        GLD16(w2g + (src >> 1), (u16*)w2s[(e + 1) & 1] + (o >> 1));
      }
      asm volatile("s_waitcnt vmcnt(8)" ::: "memory");   // current slab resident
    } else {
      asm volatile("s_waitcnt vmcnt(0)" ::: "memory");
    }
    asm volatile("s_barrier" ::: "memory");
    const char* wb = (const char*)w2s[e & 1];
    f32x4 acc[4] = {};
#pragma unroll
    for (int kk = 0; kk < 4; kk++) {
      bf16x8 a = *(const bf16x8*)&E1s[mh * 16 + lm][e * 128 + kk * 32 + lq * 8];
#pragma unroll
      for (int j = 0; j < 4; j++) {
        int n = nh * 64 + 16 * j + lm;
        int ba = (n * 256 + kk * 64 + lq * 16) ^ ((n & 7) << 4);
        bf16x8 b = *(const bf16x8*)(wb + ba);
        acc[j] = MFMA16(a, b, acc[j]);
      }
    }
#pragma unroll
    for (int j = 0; j < 4; j++)
#pragma unroll
      for (int rr = 0; rr < 4; rr++) {
        float v = tanhfast(acc[j][rr] + b2v[e][j]);
        moeacc[j][rr] += rws[(mh * 16 + lq * 4 + rr) * 5 + e] * v;
      }
    asm volatile("s_barrier" ::: "memory");  // slab consumed; safe to overwrite next iter
  }
  __syncthreads();                     // done reading E1s
  float* moes = (float*)&E1s[0][0];    // [32][132]
#pragma unroll
  for (int j = 0; j < 4; j++)
#pragma unroll
    for (int rr = 0; rr < 4; rr++)
      moes[(mh * 16 + lq * 4 + rr) * 132 + nh * 64 + 16 * j + lm] = moeacc[j][rr];
  __syncthreads();
  float* parts = moes + 32 * 132;      // [32][4][10]
  if (t < 128) {
    int row = t >> 2, qc = t & 3;
    float pl[10] = {};
    for (int cc = qc * 32; cc < qc * 32 + 32; cc++) {
      float mv = moes[row * 132 + cc];
#pragma unroll
      for (int cls = 0; cls < 10; cls++) pl[cls] += mv * wssh[cc * 10 + cls];
    }
#pragma unroll
    for (int cls = 0; cls < 10; cls++) parts[(row * 4 + qc) * 10 + cls] = pl[cls];
  }
  __syncthreads();
  if (t < 32) {
    float lg[10];
    float mx = -1e30f;
#pragma unroll
    for (int cls = 0; cls < 10; cls++) {
      lg[cls] = parts[(t * 4) * 10 + cls] + parts[(t * 4 + 1) * 10 + cls] +
                parts[(t * 4 + 2) * 10 + cls] + parts[(t * 4 + 3) * 10 + cls] + bs[cls];
      mx = fmaxf(mx, lg[cls]);
    }
    float sum = 0.f;
#pragma unroll
    for (int cls = 0; cls < 10; cls++) { lg[cls] = __expf(lg[cls] - mx); sum += lg[cls]; }
    float inv = 1.f / sum;
    float* orow = out + (size_t)(r0 + t) * 10;
#pragma unroll
    for (int cls = 0; cls < 10; cls++) orow[cls] = lg[cls] * inv;
  }
}

extern "C" void kernel_launch(void* const* d_in, const int* in_sizes, int n_in,
                              void* d_out, int out_size, void* d_ws, size_t ws_size,
                              hipStream_t stream) {
  const float* x    = (const float*)d_in[0];
  const float* c1w  = (const float*)d_in[1];
  const float* c1b  = (const float*)d_in[2];
  const float* c2w  = (const float*)d_in[3];
  const float* c2b  = (const float*)d_in[4];
  const float* Wg   = (const float*)d_in[5];
  const float* bg   = (const float*)d_in[6];
  const float* Wglu = (const float*)d_in[7];
  const float* bglu = (const float*)d_in[8];
  const float* W1e  = (const float*)d_in[9];
  const float* b1e  = (const float*)d_in[10];
  const float* W2e  = (const float*)d_in[11];
  const float* b2e  = (const float*)d_in[12];
  const float* Wsp  = (const float*)d_in[13];
  const float* bsp  = (const float*)d_in[14];
  char* ws = (char*)d_ws;
  u16* e1b     = (u16*)(ws + 0);
  u16* feat    = (u16*)(ws + 37748736);
  u16* W1T     = (u16*)(ws + 90177536);
  u16* W2T     = (u16*)(ws + 94273536);
  u16* W2colF  = (u16*)(ws + 94437376);
  u16* WcatT   = (u16*)(ws + 94447616);
  float* rw    = (float*)(ws + 94550016);

  prep_kernel<<<1540, 256, 0, stream>>>(c2w, Wg, Wglu, W2e, W1e,
                                        W2colF, WcatT, W2T, W1T);
  conv_fused_kernel<<<1024, 256, 0, stream>>>(x, c1w, c1b, W2colF, c2b, feat);
  gemm1_kernel<<<320, 256, 0, stream>>>(feat, W1T, WcatT, b1e, bg, bglu, e1b, rw);
  gemm2_head_kernel<<<256, 256, 0, stream>>>(e1b, W2T, b2e, rw, Wsp, bsp,
                                             (float*)d_out);
}